// Round 1
// baseline (469.416 us; speedup 1.0000x reference)
//
#include <hip/hip_runtime.h>

typedef __attribute__((ext_vector_type(8))) short short8;
typedef __attribute__((ext_vector_type(4))) float f32x4;

// ---------- helpers ----------
__device__ __forceinline__ unsigned short f2bf(float f) {
  union { float f; unsigned int u; } v;
  v.f = f;
  unsigned int u = v.u;
  u += 0x7FFFu + ((u >> 16) & 1u);   // round-to-nearest-even
  return (unsigned short)(u >> 16);
}

__device__ __forceinline__ short8 pack8(float4 a, float4 b) {
  short8 r;
  r[0] = (short)f2bf(a.x); r[1] = (short)f2bf(a.y);
  r[2] = (short)f2bf(a.z); r[3] = (short)f2bf(a.w);
  r[4] = (short)f2bf(b.x); r[5] = (short)f2bf(b.y);
  r[6] = (short)f2bf(b.z); r[7] = (short)f2bf(b.w);
  return r;
}

// ---------- kernel 1: per-ref-row squared norm + concat labels ----------
__global__ void prep_kernel(const float* __restrict__ emb,
                            const int* __restrict__ labels,
                            const float* __restrict__ emb_mem,
                            const int* __restrict__ lbl_mem,
                            float* __restrict__ sqb, int* __restrict__ reflab,
                            int Bn, int Dn) {
  int j = blockIdx.x;
  int lane = threadIdx.x;  // 64 threads = 1 wave
  const float* src = (j < Bn) ? (emb + (size_t)j * Dn)
                              : (emb_mem + (size_t)(j - Bn) * Dn);
  float s = 0.f;
  int nf4 = Dn >> 2;
  for (int c = lane; c < nf4; c += 64) {
    float4 v = ((const float4*)src)[c];
    s += v.x * v.x + v.y * v.y + v.z * v.z + v.w * v.w;
  }
#pragma unroll
  for (int off = 32; off; off >>= 1) s += __shfl_xor(s, off);
  if (lane == 0) {
    sqb[j] = s;
    reflab[j] = (j < Bn) ? labels[j] : lbl_mem[j - Bn];
  }
}

// ---------- kernel 2: fused bf16 MFMA GEMM + masked row reduction ----------
#define BM 128
#define BN 128
#define BK 32
#define LDK 40  // padded LDS leading dim (bf16 elems): minimal 8-way bank spread

__global__ __launch_bounds__(256)
void gemm_epi_kernel(const float* __restrict__ emb,
                     const float* __restrict__ emb_mem,
                     const float* __restrict__ sqb,
                     const int* __restrict__ reflab,
                     float* __restrict__ rowacc,
                     int Bn, int Dn, int Mn, int mtiles, int ntiles) {
  __shared__ unsigned short As[BM * LDK];
  __shared__ unsigned short Bs[BN * LDK];

  int bid = blockIdx.x;
  int it, jt;
  if (mtiles == 8 && (ntiles & 7) == 0) {
    // XCD-aware swizzle: bid%8 ~ XCD; give each XCD its own j-tile range and
    // run all 8 i-tiles of one j-tile back-to-back (B-tile L2 reuse).
    int c = bid & 7, g = bid >> 3;
    int per = ntiles >> 3;            // j-tiles per XCD (32)
    jt = c * per + (g >> 3);
    it = g & 7;
  } else {
    it = bid % mtiles;
    jt = bid / mtiles;
  }
  int rowBase = it * BM;
  int colBase = jt * BN;

  int tid = threadIdx.x;
  int lane = tid & 63, w = tid >> 6;
  int wr = w >> 1, wc = w & 1;          // 2x2 wave grid, 64x64 per wave
  int l16 = lane & 15, quad = lane >> 4;

  // staging: thread -> (row, 16-float half of BK)
  int trow = tid >> 1;
  int thalf = tid & 1;
  const float* aSrc = emb + (size_t)(rowBase + trow) * Dn + thalf * 16;
  int bj = colBase + trow;
  const float* bSrcBase = (bj < Bn) ? (emb + (size_t)bj * Dn)
                                    : (emb_mem + (size_t)(bj - Bn) * Dn);
  const float* bSrc = bSrcBase + thalf * 16;
  unsigned short* aDst = &As[trow * LDK + thalf * 16];
  unsigned short* bDst = &Bs[trow * LDK + thalf * 16];

  f32x4 acc[4][4] = {};

  for (int k0 = 0; k0 < Dn; k0 += BK) {
    const float4* a4 = (const float4*)(aSrc + k0);
    const float4* b4 = (const float4*)(bSrc + k0);
    float4 av0 = a4[0], av1 = a4[1], av2 = a4[2], av3 = a4[3];
    float4 bv0 = b4[0], bv1 = b4[1], bv2 = b4[2], bv3 = b4[3];
    *(short8*)(aDst)     = pack8(av0, av1);
    *(short8*)(aDst + 8) = pack8(av2, av3);
    *(short8*)(bDst)     = pack8(bv0, bv1);
    *(short8*)(bDst + 8) = pack8(bv2, bv3);
    __syncthreads();

    short8 af[4], bf[4];
#pragma unroll
    for (int mi = 0; mi < 4; ++mi)
      af[mi] = *(const short8*)&As[(wr * 64 + mi * 16 + l16) * LDK + quad * 8];
#pragma unroll
    for (int ni = 0; ni < 4; ++ni)
      bf[ni] = *(const short8*)&Bs[(wc * 64 + ni * 16 + l16) * LDK + quad * 8];
#pragma unroll
    for (int mi = 0; mi < 4; ++mi)
#pragma unroll
      for (int ni = 0; ni < 4; ++ni)
        acc[mi][ni] = __builtin_amdgcn_mfma_f32_16x16x32_bf16(
            af[mi], bf[ni], acc[mi][ni], 0, 0, 0);
    __syncthreads();
  }

  // ---- epilogue: d = max(sqa+sqb-2*dot, 0); masked per-row accumulation ----
  float sqc[4];
  int labc[4];
#pragma unroll
  for (int ni = 0; ni < 4; ++ni) {
    int gcol = colBase + wc * 64 + ni * 16 + l16;
    sqc[ni] = sqb[gcol];
    labc[ni] = reflab[gcol];
  }
#pragma unroll
  for (int mi = 0; mi < 4; ++mi) {
    int gr0 = rowBase + wr * 64 + mi * 16 + quad * 4;
#pragma unroll
    for (int r = 0; r < 4; ++r) {
      int grow = gr0 + r;
      float sqr = sqb[grow];
      int labr = reflab[grow];
      float ps = 0.f, pc = 0.f, ns = 0.f, nc = 0.f;
#pragma unroll
      for (int ni = 0; ni < 4; ++ni) {
        int gcol = colBase + wc * 64 + ni * 16 + l16;
        float dist = sqr + sqc[ni] - 2.0f * acc[mi][ni][r];
        dist = fmaxf(dist, 0.f);
        bool self = (gcol == grow);  // idx_ref[j]!=i reduces to j!=i (i<B)
        bool same = (labc[ni] == labr);
        if (same && !self && dist > 0.f) { ps += dist; pc += 1.f; }
        if (!same && !self && dist < 1.f) { ns += 1.f - dist; nc += 1.f; }
      }
      // reduce across the 16 column lanes (stays within a quad)
#pragma unroll
      for (int off = 8; off; off >>= 1) {
        ps += __shfl_xor(ps, off);
        pc += __shfl_xor(pc, off);
        ns += __shfl_xor(ns, off);
        nc += __shfl_xor(nc, off);
      }
      if (l16 == 0) {
        atomicAdd(&rowacc[grow * 4 + 0], ps);
        atomicAdd(&rowacc[grow * 4 + 1], pc);
        atomicAdd(&rowacc[grow * 4 + 2], ns);
        atomicAdd(&rowacc[grow * 4 + 3], nc);
      }
    }
  }
}

// ---------- kernel 3: final loss ----------
__global__ void finalize_kernel(const float* __restrict__ rowacc,
                                float* __restrict__ out, int Bn) {
  __shared__ float red[4];
  int tid = threadIdx.x;  // 256
  float v = 0.f;
  for (int i = tid; i < Bn; i += 256) {
    float sp = rowacc[i * 4 + 0], cp = rowacc[i * 4 + 1];
    float sn = rowacc[i * 4 + 2], cn = rowacc[i * 4 + 3];
    v += sp / (cp + 1e-6f) + sn / (cn + 1e-6f);
  }
#pragma unroll
  for (int off = 32; off; off >>= 1) v += __shfl_xor(v, off);
  if ((tid & 63) == 0) red[tid >> 6] = v;
  __syncthreads();
  if (tid == 0) out[0] = (red[0] + red[1] + red[2] + red[3]) / (float)Bn;
}

// ---------- host ----------
extern "C" void kernel_launch(void* const* d_in, const int* in_sizes, int n_in,
                              void* d_out, int out_size, void* d_ws, size_t ws_size,
                              hipStream_t stream) {
  const float* emb     = (const float*)d_in[0];
  const int*   labels  = (const int*)d_in[1];
  const float* emb_mem = (const float*)d_in[2];
  const int*   lbl_mem = (const int*)d_in[3];
  // d_in[4] (add_to_mem) does not affect the returned loss.

  int Bn = in_sizes[1];
  int Dn = in_sizes[0] / Bn;
  int Rn = in_sizes[3];
  int Mn = Bn + Rn;

  char* ws = (char*)d_ws;
  float* sqb    = (float*)ws;                       // Mn floats
  int*   reflab = (int*)(ws + (size_t)Mn * 4);      // Mn ints
  float* rowacc = (float*)(ws + (size_t)Mn * 8);    // Bn*4 floats

  hipMemsetAsync(rowacc, 0, (size_t)Bn * 4 * sizeof(float), stream);
  prep_kernel<<<Mn, 64, 0, stream>>>(emb, labels, emb_mem, lbl_mem, sqb, reflab, Bn, Dn);

  int mtiles = Bn / BM, ntiles = Mn / BN;
  gemm_epi_kernel<<<mtiles * ntiles, 256, 0, stream>>>(
      emb, emb_mem, sqb, reflab, rowacc, Bn, Dn, Mn, mtiles, ntiles);

  finalize_kernel<<<1, 256, 0, stream>>>(rowacc, (float*)d_out, Bn);
}

// Round 2
// 465.991 us; speedup vs baseline: 1.0074x; 1.0074x over previous
//
#include <hip/hip_runtime.h>

typedef __attribute__((ext_vector_type(8))) short short8;
typedef __attribute__((ext_vector_type(4))) float f32x4;

// async global->LDS, 16B per lane, dest = wave-uniform base + lane*16
#define GLOAD16(g, l)                                                        \
  __builtin_amdgcn_global_load_lds(                                          \
      (const __attribute__((address_space(1))) unsigned int*)(g),            \
      (__attribute__((address_space(3))) unsigned int*)(l), 16, 0, 0)

__device__ __forceinline__ unsigned short f2bf(float f) {
  union { float f; unsigned int u; } v;
  v.f = f;
  unsigned int u = v.u;
  u += 0x7FFFu + ((u >> 16) & 1u);  // round-to-nearest-even
  return (unsigned short)(u >> 16);
}

__device__ __forceinline__ short8 pack8(float4 a, float4 b) {
  short8 r;
  r[0] = (short)f2bf(a.x); r[1] = (short)f2bf(a.y);
  r[2] = (short)f2bf(a.z); r[3] = (short)f2bf(a.w);
  r[4] = (short)f2bf(b.x); r[5] = (short)f2bf(b.y);
  r[6] = (short)f2bf(b.z); r[7] = (short)f2bf(b.w);
  return r;
}

// ---------- kernel 1: fp32 -> contiguous bf16 rows + sq-norms + labels ----
// 1 wave per row (D=512 -> 8 floats/lane), coalesced read + coalesced write.
__global__ __launch_bounds__(256)
void prep2_kernel(const float* __restrict__ emb, const int* __restrict__ labels,
                  const float* __restrict__ emb_mem, const int* __restrict__ lbl_mem,
                  unsigned short* __restrict__ refbf, float* __restrict__ sqb,
                  int* __restrict__ reflab, int Bn, int Dn, int Mn) {
  int wid = threadIdx.x >> 6, lane = threadIdx.x & 63;
  int row = blockIdx.x * 4 + wid;
  if (row >= Mn) return;
  const float* src = (row < Bn) ? (emb + (size_t)row * Dn)
                                : (emb_mem + (size_t)(row - Bn) * Dn);
  unsigned short* dst = refbf + (size_t)row * Dn;
  float s = 0.f;
  for (int c0 = lane * 8; c0 < Dn; c0 += 64 * 8) {
    float4 v0 = ((const float4*)(src + c0))[0];
    float4 v1 = ((const float4*)(src + c0))[1];
    s += v0.x * v0.x + v0.y * v0.y + v0.z * v0.z + v0.w * v0.w;
    s += v1.x * v1.x + v1.y * v1.y + v1.z * v1.z + v1.w * v1.w;
    *(short8*)(dst + c0) = pack8(v0, v1);
  }
#pragma unroll
  for (int off = 32; off; off >>= 1) s += __shfl_xor(s, off);
  if (lane == 0) {
    sqb[row] = s;
    reflab[row] = (row < Bn) ? labels[row] : lbl_mem[row - Bn];
  }
}

// ---------- kernel 2: bf16 MFMA GEMM (m97-style staging) + masked epilogue --
#define BM 128
#define BN 128
#define BK 32   // 32 bf16 = 64B per row; A/B tile = 8KB each, no padding
                // (global_load_lds requires lane-contiguous LDS layout)

__global__ __launch_bounds__(256)
void gemm_epi_kernel(const unsigned short* __restrict__ refbf,
                     const float* __restrict__ sqb,
                     const int* __restrict__ reflab,
                     float* __restrict__ rowacc,
                     int Dn, int mtiles, int ntiles) {
  __shared__ unsigned short As[BM * BK];
  __shared__ unsigned short Bs[BN * BK];

  int bid = blockIdx.x;
  int it, jt;
  if (mtiles == 8 && (ntiles & 7) == 0) {
    // XCD swizzle: bid%8 ~ XCD; within an XCD run the 8 i-tiles of one j-tile
    // back-to-back so the B-tile is fetched once into that XCD's L2.
    int c = bid & 7, g = bid >> 3;
    int per = ntiles >> 3;
    jt = c * per + (g >> 3);
    it = g & 7;
  } else {
    it = bid % mtiles;
    jt = bid / mtiles;
  }
  int rowBase = it * BM;
  int colBase = jt * BN;

  int tid = threadIdx.x, lane = tid & 63, w = tid >> 6;
  int wr = w >> 1, wc = w & 1;       // 2x2 wave grid, 64x64 per wave
  int l16 = lane & 15, quad = lane >> 4;

  // staging: wave w stages tile rows [w*32, w*32+32); 4 lanes per row,
  // lane&3 picks the 16B chunk. LDS dest = wave base + lane*16 (HW rule).
  int lrow = lane >> 2, lk = lane & 3;
  size_t rowB = (size_t)Dn * 2;  // bytes per refbf row
  const char* gA0 = (const char*)refbf + (size_t)(rowBase + w * 32 + lrow) * rowB + lk * 16;
  const char* gA1 = gA0 + 16 * rowB;
  const char* gB0 = (const char*)refbf + (size_t)(colBase + w * 32 + lrow) * rowB + lk * 16;
  const char* gB1 = gB0 + 16 * rowB;
  char* lA = (char*)As + w * 2048;
  char* lB = (char*)Bs + w * 2048;

  f32x4 acc[4][4] = {};

  for (int k0 = 0; k0 < Dn; k0 += BK) {
    int koff = k0 * 2;
    GLOAD16(gA0 + koff, lA);
    GLOAD16(gA1 + koff, lA + 1024);
    GLOAD16(gB0 + koff, lB);
    GLOAD16(gB1 + koff, lB + 1024);
    __syncthreads();  // compiler emits vmcnt(0) drain before s_barrier

    short8 af[4], bfr[4];
#pragma unroll
    for (int mi = 0; mi < 4; ++mi)
      af[mi] = *(const short8*)&As[(wr * 64 + mi * 16 + l16) * BK + quad * 8];
#pragma unroll
    for (int ni = 0; ni < 4; ++ni)
      bfr[ni] = *(const short8*)&Bs[(wc * 64 + ni * 16 + l16) * BK + quad * 8];
#pragma unroll
    for (int mi = 0; mi < 4; ++mi)
#pragma unroll
      for (int ni = 0; ni < 4; ++ni)
        acc[mi][ni] = __builtin_amdgcn_mfma_f32_16x16x32_bf16(
            af[mi], bfr[ni], acc[mi][ni], 0, 0, 0);
    __syncthreads();
  }

  // ---- epilogue: d = max(sqa+sqb-2*dot, 0); masked per-row accumulation ----
  float sqc[4];
  int labc[4];
#pragma unroll
  for (int ni = 0; ni < 4; ++ni) {
    int gcol = colBase + wc * 64 + ni * 16 + l16;
    sqc[ni] = sqb[gcol];
    labc[ni] = reflab[gcol];
  }
#pragma unroll
  for (int mi = 0; mi < 4; ++mi) {
    int gr0 = rowBase + wr * 64 + mi * 16 + quad * 4;
#pragma unroll
    for (int r = 0; r < 4; ++r) {
      int grow = gr0 + r;
      float sqr = sqb[grow];
      int labr = reflab[grow];
      float ps = 0.f, pc = 0.f, ns = 0.f, nc = 0.f;
#pragma unroll
      for (int ni = 0; ni < 4; ++ni) {
        int gcol = colBase + wc * 64 + ni * 16 + l16;
        float dist = sqr + sqc[ni] - 2.0f * acc[mi][ni][r];
        dist = fmaxf(dist, 0.f);
        bool self = (gcol == grow);  // idx_ref[j]!=i reduces to j!=i (i<B)
        bool same = (labc[ni] == labr);
        if (same && !self && dist > 0.f) { ps += dist; pc += 1.f; }
        if (!same && !self && dist < 1.f) { ns += 1.f - dist; nc += 1.f; }
      }
#pragma unroll
      for (int off = 8; off; off >>= 1) {
        ps += __shfl_xor(ps, off);
        pc += __shfl_xor(pc, off);
        ns += __shfl_xor(ns, off);
        nc += __shfl_xor(nc, off);
      }
      if (l16 == 0) {
        atomicAdd(&rowacc[grow * 4 + 0], ps);
        atomicAdd(&rowacc[grow * 4 + 1], pc);
        atomicAdd(&rowacc[grow * 4 + 2], ns);
        atomicAdd(&rowacc[grow * 4 + 3], nc);
      }
    }
  }
}

// ---------- kernel 3: final loss ----------
__global__ void finalize_kernel(const float* __restrict__ rowacc,
                                float* __restrict__ out, int Bn) {
  __shared__ float red[4];
  int tid = threadIdx.x;  // 256
  float v = 0.f;
  for (int i = tid; i < Bn; i += 256) {
    float sp = rowacc[i * 4 + 0], cp = rowacc[i * 4 + 1];
    float sn = rowacc[i * 4 + 2], cn = rowacc[i * 4 + 3];
    v += sp / (cp + 1e-6f) + sn / (cn + 1e-6f);
  }
#pragma unroll
  for (int off = 32; off; off >>= 1) v += __shfl_xor(v, off);
  if ((tid & 63) == 0) red[tid >> 6] = v;
  __syncthreads();
  if (tid == 0) out[0] = (red[0] + red[1] + red[2] + red[3]) / (float)Bn;
}

// ---------- host ----------
extern "C" void kernel_launch(void* const* d_in, const int* in_sizes, int n_in,
                              void* d_out, int out_size, void* d_ws, size_t ws_size,
                              hipStream_t stream) {
  const float* emb     = (const float*)d_in[0];
  const int*   labels  = (const int*)d_in[1];
  const float* emb_mem = (const float*)d_in[2];
  const int*   lbl_mem = (const int*)d_in[3];
  // d_in[4] (add_to_mem) does not affect the returned loss.

  int Bn = in_sizes[1];
  int Dn = in_sizes[0] / Bn;
  int Rn = in_sizes[3];
  int Mn = Bn + Rn;

  char* ws = (char*)d_ws;
  unsigned short* refbf = (unsigned short*)ws;                 // Mn*Dn bf16
  size_t off = (size_t)Mn * Dn * 2;
  float* sqb    = (float*)(ws + off);                          // Mn floats
  int*   reflab = (int*)(ws + off + (size_t)Mn * 4);           // Mn ints
  float* rowacc = (float*)(ws + off + (size_t)Mn * 8);         // Bn*4 floats

  hipMemsetAsync(rowacc, 0, (size_t)Bn * 4 * sizeof(float), stream);
  prep2_kernel<<<(Mn + 3) / 4, 256, 0, stream>>>(
      emb, labels, emb_mem, lbl_mem, refbf, sqb, reflab, Bn, Dn, Mn);

  int mtiles = Bn / BM, ntiles = Mn / BN;
  gemm_epi_kernel<<<mtiles * ntiles, 256, 0, stream>>>(
      refbf, sqb, reflab, rowacc, Dn, mtiles, ntiles);

  finalize_kernel<<<1, 256, 0, stream>>>(rowacc, (float*)d_out, Bn);
}

// Round 3
// 177.775 us; speedup vs baseline: 2.6405x; 2.6212x over previous
//
#include <hip/hip_runtime.h>

typedef __attribute__((ext_vector_type(8))) short short8;
typedef __attribute__((ext_vector_type(4))) float f32x4;

// async global->LDS, 16B per lane, dest = wave-uniform base + lane*16
#define GLOAD16(g, l)                                                        \
  __builtin_amdgcn_global_load_lds(                                          \
      (const __attribute__((address_space(1))) unsigned int*)(g),            \
      (__attribute__((address_space(3))) unsigned int*)(l), 16, 0, 0)

__device__ __forceinline__ unsigned short f2bf(float f) {
  union { float f; unsigned int u; } v;
  v.f = f;
  unsigned int u = v.u;
  u += 0x7FFFu + ((u >> 16) & 1u);  // round-to-nearest-even
  return (unsigned short)(u >> 16);
}

__device__ __forceinline__ short8 pack8(float4 a, float4 b) {
  short8 r;
  r[0] = (short)f2bf(a.x); r[1] = (short)f2bf(a.y);
  r[2] = (short)f2bf(a.z); r[3] = (short)f2bf(a.w);
  r[4] = (short)f2bf(b.x); r[5] = (short)f2bf(b.y);
  r[6] = (short)f2bf(b.z); r[7] = (short)f2bf(b.w);
  return r;
}

// ---------- kernel 1: fp32 -> contiguous bf16 rows + sq-norms + labels ----
__global__ __launch_bounds__(256)
void prep2_kernel(const float* __restrict__ emb, const int* __restrict__ labels,
                  const float* __restrict__ emb_mem, const int* __restrict__ lbl_mem,
                  unsigned short* __restrict__ refbf, float* __restrict__ sqb,
                  int* __restrict__ reflab, int Bn, int Dn, int Mn) {
  int wid = threadIdx.x >> 6, lane = threadIdx.x & 63;
  int row = blockIdx.x * 4 + wid;
  if (row >= Mn) return;
  const float* src = (row < Bn) ? (emb + (size_t)row * Dn)
                                : (emb_mem + (size_t)(row - Bn) * Dn);
  unsigned short* dst = refbf + (size_t)row * Dn;
  float s = 0.f;
  for (int c0 = lane * 8; c0 < Dn; c0 += 64 * 8) {
    float4 v0 = ((const float4*)(src + c0))[0];
    float4 v1 = ((const float4*)(src + c0))[1];
    s += v0.x * v0.x + v0.y * v0.y + v0.z * v0.z + v0.w * v0.w;
    s += v1.x * v1.x + v1.y * v1.y + v1.z * v1.z + v1.w * v1.w;
    *(short8*)(dst + c0) = pack8(v0, v1);
  }
#pragma unroll
  for (int off = 32; off; off >>= 1) s += __shfl_xor(s, off);
  if (lane == 0) {
    sqb[row] = s;
    reflab[row] = (row < Bn) ? labels[row] : lbl_mem[row - Bn];
  }
}

// ---------- kernel 2: bf16 MFMA GEMM + masked epilogue (NO global atomics) --
#define BM 128
#define BN 128
#define BK 32   // 64B per tile row in LDS

__global__ __launch_bounds__(256)
void gemm_epi_kernel(const unsigned short* __restrict__ refbf,
                     const float* __restrict__ sqb,
                     const int* __restrict__ reflab,
                     float* __restrict__ part,
                     int Dn, int mtiles, int ntiles) {
  __shared__ unsigned short As[BM * BK];
  __shared__ unsigned short Bs[BN * BK];
  __shared__ float redbuf[2 * BM * 4];  // [wave-col][row][4 counters]

  int bid = blockIdx.x;
  int it, jt;
  if (mtiles == 8 && (ntiles & 7) == 0) {
    int c = bid & 7, g = bid >> 3;
    int per = ntiles >> 3;
    jt = c * per + (g >> 3);
    it = g & 7;
  } else {
    it = bid % mtiles;
    jt = bid / mtiles;
  }
  int rowBase = it * BM;
  int colBase = jt * BN;

  int tid = threadIdx.x, lane = tid & 63, w = tid >> 6;
  int wr = w >> 1, wc = w & 1;       // 2x2 wave grid, 64x64 per wave
  int l16 = lane & 15, quad = lane >> 4;

  // staging: wave w stages tile rows [w*32, w*32+32); 4 lanes/row; the 16B
  // chunk each lane fetches is rotated by row (c = (lk - (r>>1)) & 3) so the
  // *read* side is bank-conflict-free. LDS dest is HW-fixed: base + lane*16.
  int lrow = lane >> 2, lk = lane & 3;
  size_t rowB = (size_t)Dn * 2;
  int r0 = w * 32 + lrow;
  int ca = (lk - (r0 >> 1)) & 3;  // same for r0+16 (shift by 8 == 0 mod 4)
  const char* gA0 = (const char*)refbf + (size_t)(rowBase + r0) * rowB + ca * 16;
  const char* gA1 = gA0 + 16 * rowB;
  const char* gB0 = (const char*)refbf + (size_t)(colBase + r0) * rowB + ca * 16;
  const char* gB1 = gB0 + 16 * rowB;
  char* lA = (char*)As + w * 2048;
  char* lB = (char*)Bs + w * 2048;

  f32x4 acc[4][4] = {};

  for (int k0 = 0; k0 < Dn; k0 += BK) {
    int koff = k0 * 2;
    GLOAD16(gA0 + koff, lA);
    GLOAD16(gA1 + koff, lA + 1024);
    GLOAD16(gB0 + koff, lB);
    GLOAD16(gB1 + koff, lB + 1024);
    __syncthreads();

    short8 af[4], bfr[4];
#pragma unroll
    for (int mi = 0; mi < 4; ++mi) {
      int row = wr * 64 + mi * 16 + l16;
      af[mi] = *(const short8*)&As[row * BK + ((quad + (row >> 1)) & 3) * 8];
    }
#pragma unroll
    for (int ni = 0; ni < 4; ++ni) {
      int row = wc * 64 + ni * 16 + l16;
      bfr[ni] = *(const short8*)&Bs[row * BK + ((quad + (row >> 1)) & 3) * 8];
    }
#pragma unroll
    for (int mi = 0; mi < 4; ++mi)
#pragma unroll
      for (int ni = 0; ni < 4; ++ni)
        acc[mi][ni] = __builtin_amdgcn_mfma_f32_16x16x32_bf16(
            af[mi], bfr[ni], acc[mi][ni], 0, 0, 0);
    __syncthreads();
  }

  // ---- epilogue: d = max(sqa+sqb-2*dot, 0); per-row masked partials ------
  float sqc[4];
  int labc[4];
#pragma unroll
  for (int ni = 0; ni < 4; ++ni) {
    int gcol = colBase + wc * 64 + ni * 16 + l16;
    sqc[ni] = sqb[gcol];
    labc[ni] = reflab[gcol];
  }
#pragma unroll
  for (int mi = 0; mi < 4; ++mi) {
    int lr0 = wr * 64 + mi * 16 + quad * 4;
#pragma unroll
    for (int r = 0; r < 4; ++r) {
      int lrow_loc = lr0 + r;
      int grow = rowBase + lrow_loc;
      float sqr = sqb[grow];
      int labr = reflab[grow];
      float ps = 0.f, pc = 0.f, ns = 0.f, nc = 0.f;
#pragma unroll
      for (int ni = 0; ni < 4; ++ni) {
        int gcol = colBase + wc * 64 + ni * 16 + l16;
        float dist = sqr + sqc[ni] - 2.0f * acc[mi][ni][r];
        dist = fmaxf(dist, 0.f);
        bool self = (gcol == grow);  // idx_ref[j]!=i reduces to j!=i
        bool same = (labc[ni] == labr);
        if (same && !self && dist > 0.f) { ps += dist; pc += 1.f; }
        if (!same && !self && dist < 1.f) { ns += 1.f - dist; nc += 1.f; }
      }
#pragma unroll
      for (int off = 8; off; off >>= 1) {
        ps += __shfl_xor(ps, off);
        pc += __shfl_xor(pc, off);
        ns += __shfl_xor(ns, off);
        nc += __shfl_xor(nc, off);
      }
      if (l16 == 0) {  // one lane per quad; each (wc,row) has a unique owner
        f32x4 v = {ps, pc, ns, nc};
        *(f32x4*)&redbuf[(wc * BM + lrow_loc) * 4] = v;
      }
    }
  }
  __syncthreads();
  // combine wave-cols, store one coalesced 2KB slab (no atomics anywhere)
  size_t slab = ((size_t)jt * mtiles + it) * (BM * 4);
  part[slab + tid]       = redbuf[tid]       + redbuf[BM * 4 + tid];
  part[slab + 256 + tid] = redbuf[256 + tid] + redbuf[BM * 4 + 256 + tid];
}

// ---------- kernel 3: fold j-tile partials per row ----------
__global__ __launch_bounds__(256)
void reduce_rows_kernel(const float* __restrict__ part,
                        float* __restrict__ rowloss,
                        int mtiles, int ntiles, int Bn) {
  int wid = threadIdx.x >> 6, lane = threadIdx.x & 63;
  int row = blockIdx.x * 4 + wid;
  if (row >= Bn) return;
  int it = row / BM, lr = row % BM;
  f32x4 a = {0.f, 0.f, 0.f, 0.f};
  for (int jt = lane; jt < ntiles; jt += 64) {
    f32x4 v = *(const f32x4*)&part[((size_t)jt * mtiles + it) * (BM * 4) + lr * 4];
    a[0] += v[0]; a[1] += v[1]; a[2] += v[2]; a[3] += v[3];
  }
#pragma unroll
  for (int off = 32; off; off >>= 1) {
    a[0] += __shfl_xor(a[0], off);
    a[1] += __shfl_xor(a[1], off);
    a[2] += __shfl_xor(a[2], off);
    a[3] += __shfl_xor(a[3], off);
  }
  if (lane == 0)
    rowloss[row] = a[0] / (a[1] + 1e-6f) + a[2] / (a[3] + 1e-6f);
}

// ---------- kernel 4: final sum ----------
__global__ void finalize_kernel(const float* __restrict__ rowloss,
                                float* __restrict__ out, int Bn) {
  __shared__ float red[4];
  int tid = threadIdx.x;  // 256
  float v = 0.f;
  for (int i = tid; i < Bn; i += 256) v += rowloss[i];
#pragma unroll
  for (int off = 32; off; off >>= 1) v += __shfl_xor(v, off);
  if ((tid & 63) == 0) red[tid >> 6] = v;
  __syncthreads();
  if (tid == 0) out[0] = (red[0] + red[1] + red[2] + red[3]) / (float)Bn;
}

// ---------- host ----------
extern "C" void kernel_launch(void* const* d_in, const int* in_sizes, int n_in,
                              void* d_out, int out_size, void* d_ws, size_t ws_size,
                              hipStream_t stream) {
  const float* emb     = (const float*)d_in[0];
  const int*   labels  = (const int*)d_in[1];
  const float* emb_mem = (const float*)d_in[2];
  const int*   lbl_mem = (const int*)d_in[3];
  // d_in[4] (add_to_mem) does not affect the returned loss.

  int Bn = in_sizes[1];
  int Dn = in_sizes[0] / Bn;
  int Rn = in_sizes[3];
  int Mn = Bn + Rn;
  int mtiles = Bn / BM, ntiles = Mn / BN;

  char* ws = (char*)d_ws;
  unsigned short* refbf = (unsigned short*)ws;                  // Mn*Dn bf16
  size_t off = (size_t)Mn * Dn * 2;
  float* sqb    = (float*)(ws + off);                           // Mn floats
  int*   reflab = (int*)(ws + off + (size_t)Mn * 4);            // Mn ints
  float* part   = (float*)(ws + off + (size_t)Mn * 8);          // ntiles*mtiles*512
  float* rowloss= part + (size_t)ntiles * mtiles * (BM * 4);    // Bn floats

  prep2_kernel<<<(Mn + 3) / 4, 256, 0, stream>>>(
      emb, labels, emb_mem, lbl_mem, refbf, sqb, reflab, Bn, Dn, Mn);

  gemm_epi_kernel<<<mtiles * ntiles, 256, 0, stream>>>(
      refbf, sqb, reflab, part, Dn, mtiles, ntiles);

  reduce_rows_kernel<<<(Bn + 3) / 4, 256, 0, stream>>>(
      part, rowloss, mtiles, ntiles, Bn);

  finalize_kernel<<<1, 256, 0, stream>>>(rowloss, (float*)d_out, Bn);
}

// Round 5
// 163.977 us; speedup vs baseline: 2.8627x; 1.0841x over previous
//
#include <hip/hip_runtime.h>

typedef __attribute__((ext_vector_type(8))) short short8;
typedef __attribute__((ext_vector_type(4))) float f32x4;

// async global->LDS, 16B per lane, dest = wave-uniform base + lane*16
#define GLOAD16(g, l)                                                        \
  __builtin_amdgcn_global_load_lds(                                          \
      (const __attribute__((address_space(1))) unsigned int*)(g),            \
      (__attribute__((address_space(3))) unsigned int*)(l), 16, 0, 0)

__device__ __forceinline__ unsigned short f2bf(float f) {
  union { float f; unsigned int u; } v;
  v.f = f;
  unsigned int u = v.u;
  u += 0x7FFFu + ((u >> 16) & 1u);  // round-to-nearest-even
  return (unsigned short)(u >> 16);
}

__device__ __forceinline__ short8 pack8(float4 a, float4 b) {
  short8 r;
  r[0] = (short)f2bf(a.x); r[1] = (short)f2bf(a.y);
  r[2] = (short)f2bf(a.z); r[3] = (short)f2bf(a.w);
  r[4] = (short)f2bf(b.x); r[5] = (short)f2bf(b.y);
  r[6] = (short)f2bf(b.z); r[7] = (short)f2bf(b.w);
  return r;
}

#define BM 128
#define BN 128
#define BK 32

// ---------- kernel 1: fp32 -> bf16 + sq-norms + labels + zero-init finals --
__global__ __launch_bounds__(256)
void prep2_kernel(const float* __restrict__ emb, const int* __restrict__ labels,
                  const float* __restrict__ emb_mem, const int* __restrict__ lbl_mem,
                  unsigned short* __restrict__ refbf, float* __restrict__ sqb,
                  int* __restrict__ reflab, float* __restrict__ facc,
                  int* __restrict__ fcnt, int Bn, int Dn, int Mn) {
  if (blockIdx.x == 0 && threadIdx.x == 0) { *facc = 0.f; *fcnt = 0; }
  int wid = threadIdx.x >> 6, lane = threadIdx.x & 63;
  int row = blockIdx.x * 4 + wid;
  if (row >= Mn) return;
  const float* src = (row < Bn) ? (emb + (size_t)row * Dn)
                                : (emb_mem + (size_t)(row - Bn) * Dn);
  unsigned short* dst = refbf + (size_t)row * Dn;
  float s = 0.f;
  for (int c0 = lane * 8; c0 < Dn; c0 += 64 * 8) {
    float4 v0 = ((const float4*)(src + c0))[0];
    float4 v1 = ((const float4*)(src + c0))[1];
    s += v0.x * v0.x + v0.y * v0.y + v0.z * v0.z + v0.w * v0.w;
    s += v1.x * v1.x + v1.y * v1.y + v1.z * v1.z + v1.w * v1.w;
    *(short8*)(dst + c0) = pack8(v0, v1);
  }
#pragma unroll
  for (int off = 32; off; off >>= 1) s += __shfl_xor(s, off);
  if (lane == 0) {
    sqb[row] = s;
    reflab[row] = (row < Bn) ? labels[row] : lbl_mem[row - Bn];
  }
}

// ---------- kernel 2a: specialized GEMM (Dn=512, 8x256 tiles) --------------
__global__ __launch_bounds__(256)
void gemm512_kernel(const unsigned short* __restrict__ refbf,
                    const float* __restrict__ sqb,
                    const int* __restrict__ reflab,
                    float* __restrict__ part) {
  // 32KB: K-loop uses [As 8K][Bs 8K]; epilogue aliases all 32K as red4.
  __shared__ __align__(16) char smem[32768];
  unsigned short* As = (unsigned short*)smem;
  unsigned short* Bs = (unsigned short*)(smem + 8192);
  f32x4* red4 = (f32x4*)smem;  // [2][128][8] f32x4

  const int ntiles = 256;
  int bid = blockIdx.x;
  int c = bid & 7, g = bid >> 3;       // validated XCD-sliced mapping (r3)
  int jt = c * 32 + (g >> 3);
  int it = g & 7;
  int rowBase = it * BM, colBase = jt * BN;

  int tid = threadIdx.x, lane = tid & 63, w = tid >> 6;
  int wr = w >> 1, wc = w & 1;
  int l16 = lane & 15, quad = lane >> 4;
  int lrow = lane >> 2, lk = lane & 3;
  int r0 = w * 32 + lrow;
  int ca = (lk - (r0 >> 1)) & 3;       // chunk rotation: conflict-free ds_read

  const char* gA0 = (const char*)refbf + (size_t)(rowBase + r0) * 1024 + ca * 16;
  const char* gA1 = gA0 + 16 * 1024;
  const char* gB0 = (const char*)refbf + (size_t)(colBase + r0) * 1024 + ca * 16;
  const char* gB1 = gB0 + 16 * 1024;
  char* lA = (char*)As + w * 2048;
  char* lB = (char*)Bs + w * 2048;

  f32x4 acc[4][4] = {};
#pragma unroll
  for (int kk = 0; kk < 16; ++kk) {     // Dn=512 / BK=32, constant offsets
    GLOAD16(gA0 + kk * 64, lA);
    GLOAD16(gA1 + kk * 64, lA + 1024);
    GLOAD16(gB0 + kk * 64, lB);
    GLOAD16(gB1 + kk * 64, lB + 1024);
    __syncthreads();
    short8 af[4], bfr[4];
#pragma unroll
    for (int mi = 0; mi < 4; ++mi) {
      int row = wr * 64 + mi * 16 + l16;
      af[mi] = *(const short8*)&As[row * BK + ((quad + (row >> 1)) & 3) * 8];
    }
#pragma unroll
    for (int ni = 0; ni < 4; ++ni) {
      int row = wc * 64 + ni * 16 + l16;
      bfr[ni] = *(const short8*)&Bs[row * BK + ((quad + (row >> 1)) & 3) * 8];
    }
#pragma unroll
    for (int mi = 0; mi < 4; ++mi)
#pragma unroll
      for (int ni = 0; ni < 4; ++ni)
        acc[mi][ni] = __builtin_amdgcn_mfma_f32_16x16x32_bf16(
            af[mi], bfr[ni], acc[mi][ni], 0, 0, 0);
    __syncthreads();
  }

  // ---- epilogue v2: packed counters, 1 shfl level, LDS fold --------------
  float sqc[4];
  int labc[4];
#pragma unroll
  for (int ni = 0; ni < 4; ++ni) {
    int gcol = colBase + wc * 64 + ni * 16 + l16;
    sqc[ni] = sqb[gcol];
    labc[ni] = reflab[gcol];
  }
#pragma unroll
  for (int mi = 0; mi < 4; ++mi) {
    int lr0 = wr * 64 + mi * 16 + quad * 4;
#pragma unroll
    for (int r = 0; r < 4; ++r) {
      int lrl = lr0 + r;
      int grow = rowBase + lrl;
      float sqr = sqb[grow];
      int labr = reflab[grow];
      float ps = 0.f, ns = 0.f, cpk = 0.f;  // cpk = pos_cnt + 512*neg_cnt
#pragma unroll
      for (int ni = 0; ni < 4; ++ni) {
        int gcol = colBase + wc * 64 + ni * 16 + l16;
        float dist = fmaxf(sqr + sqc[ni] - 2.0f * acc[mi][ni][r], 0.f);
        bool self = (gcol == grow);  // idx_ref[j]!=i reduces to j!=i
        bool same = (labc[ni] == labr);
        if (same && !self && dist > 0.f) { ps += dist; cpk += 1.f; }
        if (!same && !self && dist < 1.f) { ns += 1.f - dist; cpk += 512.f; }
      }
      ps += __shfl_xor(ps, 8);
      ns += __shfl_xor(ns, 8);
      cpk += __shfl_xor(cpk, 8);
      if (l16 < 8) {  // unique (wc,row,l16) owner; As/Bs dead past final sync
        f32x4 v = {ps, ns, cpk, 0.f};
        red4[(wc * BM + lrl) * 8 + l16] = v;
      }
    }
  }
  __syncthreads();
  if (tid < BM) {
    f32x4 s = {0.f, 0.f, 0.f, 0.f};
#pragma unroll
    for (int c2 = 0; c2 < 2; ++c2)
#pragma unroll
      for (int k = 0; k < 8; ++k)  // (k+tid)&7: lanes sweep all 32 banks
        s += red4[(c2 * BM + tid) * 8 + ((k + tid) & 7)];
    float nc = floorf(s[2] * (1.0f / 512.0f));
    float pc = s[2] - 512.f * nc;
    f32x4 o = {s[0], pc, s[1], nc};
    ((f32x4*)part)[(size_t)(rowBase + tid) * ntiles + jt] = o;  // [row][jt]
  }
}

// ---------- kernel 2b: generic GEMM (fallback for other shapes) ------------
__global__ __launch_bounds__(256)
void gemm_generic_kernel(const unsigned short* __restrict__ refbf,
                         const float* __restrict__ sqb,
                         const int* __restrict__ reflab,
                         float* __restrict__ part,
                         int Dn, int mtiles, int ntiles) {
  __shared__ unsigned short As[BM * BK];
  __shared__ unsigned short Bs[BN * BK];
  __shared__ f32x4 redbuf4[2 * BM];

  int bid = blockIdx.x;
  int it = bid % mtiles, jt = bid / mtiles;
  int rowBase = it * BM, colBase = jt * BN;
  int tid = threadIdx.x, lane = tid & 63, w = tid >> 6;
  int wr = w >> 1, wc = w & 1;
  int l16 = lane & 15, quad = lane >> 4;
  int lrow = lane >> 2, lk = lane & 3;
  size_t rowB = (size_t)Dn * 2;
  int r0 = w * 32 + lrow;
  int ca = (lk - (r0 >> 1)) & 3;
  const char* gA0 = (const char*)refbf + (size_t)(rowBase + r0) * rowB + ca * 16;
  const char* gA1 = gA0 + 16 * rowB;
  const char* gB0 = (const char*)refbf + (size_t)(colBase + r0) * rowB + ca * 16;
  const char* gB1 = gB0 + 16 * rowB;
  char* lA = (char*)As + w * 2048;
  char* lB = (char*)Bs + w * 2048;

  f32x4 acc[4][4] = {};
  for (int k0 = 0; k0 < Dn; k0 += BK) {
    int koff = k0 * 2;
    GLOAD16(gA0 + koff, lA);
    GLOAD16(gA1 + koff, lA + 1024);
    GLOAD16(gB0 + koff, lB);
    GLOAD16(gB1 + koff, lB + 1024);
    __syncthreads();
    short8 af[4], bfr[4];
#pragma unroll
    for (int mi = 0; mi < 4; ++mi) {
      int row = wr * 64 + mi * 16 + l16;
      af[mi] = *(const short8*)&As[row * BK + ((quad + (row >> 1)) & 3) * 8];
    }
#pragma unroll
    for (int ni = 0; ni < 4; ++ni) {
      int row = wc * 64 + ni * 16 + l16;
      bfr[ni] = *(const short8*)&Bs[row * BK + ((quad + (row >> 1)) & 3) * 8];
    }
#pragma unroll
    for (int mi = 0; mi < 4; ++mi)
#pragma unroll
      for (int ni = 0; ni < 4; ++ni)
        acc[mi][ni] = __builtin_amdgcn_mfma_f32_16x16x32_bf16(
            af[mi], bfr[ni], acc[mi][ni], 0, 0, 0);
    __syncthreads();
  }

  float sqc[4];
  int labc[4];
#pragma unroll
  for (int ni = 0; ni < 4; ++ni) {
    int gcol = colBase + wc * 64 + ni * 16 + l16;
    sqc[ni] = sqb[gcol];
    labc[ni] = reflab[gcol];
  }
#pragma unroll
  for (int mi = 0; mi < 4; ++mi) {
    int lr0 = wr * 64 + mi * 16 + quad * 4;
#pragma unroll
    for (int r = 0; r < 4; ++r) {
      int lrl = lr0 + r;
      int grow = rowBase + lrl;
      float sqr = sqb[grow];
      int labr = reflab[grow];
      float ps = 0.f, pc = 0.f, ns = 0.f, nc = 0.f;
#pragma unroll
      for (int ni = 0; ni < 4; ++ni) {
        int gcol = colBase + wc * 64 + ni * 16 + l16;
        float dist = fmaxf(sqr + sqc[ni] - 2.0f * acc[mi][ni][r], 0.f);
        bool self = (gcol == grow);
        bool same = (labc[ni] == labr);
        if (same && !self && dist > 0.f) { ps += dist; pc += 1.f; }
        if (!same && !self && dist < 1.f) { ns += 1.f - dist; nc += 1.f; }
      }
#pragma unroll
      for (int off = 8; off; off >>= 1) {
        ps += __shfl_xor(ps, off);
        pc += __shfl_xor(pc, off);
        ns += __shfl_xor(ns, off);
        nc += __shfl_xor(nc, off);
      }
      if (l16 == 0) {
        f32x4 v = {ps, pc, ns, nc};
        redbuf4[wc * BM + lrl] = v;
      }
    }
  }
  __syncthreads();
  if (tid < BM) {
    f32x4 s = redbuf4[tid] + redbuf4[BM + tid];
    ((f32x4*)part)[(size_t)(rowBase + tid) * ntiles + jt] = s;
  }
}

// ---------- kernel 3: per-row fold + global sum (atomic + ticket) ----------
__global__ __launch_bounds__(256)
void reduce_final_kernel(const float* __restrict__ part,
                         float* __restrict__ facc, int* __restrict__ fcnt,
                         float* __restrict__ out, int Bn, int ntiles) {
  __shared__ float rsum[4];
  int tid = threadIdx.x, w = tid >> 6, lane = tid & 63;
  int row = blockIdx.x * 4 + w;
  const f32x4* part4 = (const f32x4*)part;
  float rl = 0.f;
  if (row < Bn) {
    f32x4 a = {0.f, 0.f, 0.f, 0.f};
    for (int j = lane; j < ntiles; j += 64)
      a += part4[(size_t)row * ntiles + j];
#pragma unroll
    for (int off = 32; off; off >>= 1) {
      a[0] += __shfl_xor(a[0], off);
      a[1] += __shfl_xor(a[1], off);
      a[2] += __shfl_xor(a[2], off);
      a[3] += __shfl_xor(a[3], off);
    }
    rl = a[0] / (a[1] + 1e-6f) + a[2] / (a[3] + 1e-6f);
  }
  if (lane == 0) rsum[w] = rl;
  __syncthreads();
  if (tid == 0) {
    float bs = rsum[0] + rsum[1] + rsum[2] + rsum[3];
    atomicAdd(facc, bs);
    __threadfence();
    int old = atomicAdd(fcnt, 1);
    if (old == (int)gridDim.x - 1) {   // last block: total is complete
      __threadfence();
      float tot = atomicAdd(facc, 0.f);  // atomic read of final value
      out[0] = tot / (float)Bn;
    }
  }
}

// ---------- host ----------
extern "C" void kernel_launch(void* const* d_in, const int* in_sizes, int n_in,
                              void* d_out, int out_size, void* d_ws, size_t ws_size,
                              hipStream_t stream) {
  const float* emb     = (const float*)d_in[0];
  const int*   labels  = (const int*)d_in[1];
  const float* emb_mem = (const float*)d_in[2];
  const int*   lbl_mem = (const int*)d_in[3];
  // d_in[4] (add_to_mem) does not affect the returned loss.

  int Bn = in_sizes[1];
  int Dn = in_sizes[0] / Bn;
  int Rn = in_sizes[3];
  int Mn = Bn + Rn;
  int mtiles = Bn / BM, ntiles = Mn / BN;

  char* ws = (char*)d_ws;
  unsigned short* refbf = (unsigned short*)ws;                 // Mn*Dn bf16
  size_t off = (size_t)Mn * Dn * 2;
  float* sqb    = (float*)(ws + off);                          // Mn
  int*   reflab = (int*)(ws + off + (size_t)Mn * 4);           // Mn
  float* part   = (float*)(ws + off + (size_t)Mn * 8);         // Bn*ntiles*4
  float* facc   = part + (size_t)Bn * ntiles * 4;              // 1
  int*   fcnt   = (int*)(facc + 1);                            // 1

  prep2_kernel<<<(Mn + 3) / 4, 256, 0, stream>>>(
      emb, labels, emb_mem, lbl_mem, refbf, sqb, reflab, facc, fcnt, Bn, Dn, Mn);

  if (Dn == 512 && mtiles == 8 && ntiles == 256) {
    gemm512_kernel<<<2048, 256, 0, stream>>>(refbf, sqb, reflab, part);
  } else {
    gemm_generic_kernel<<<mtiles * ntiles, 256, 0, stream>>>(
        refbf, sqb, reflab, part, Dn, mtiles, ntiles);
  }

  reduce_final_kernel<<<(Bn + 3) / 4, 256, 0, stream>>>(
      part, facc, fcnt, (float*)d_out, Bn, ntiles);
}